// Round 2
// baseline (13.651 us; speedup 1.0000x reference)
//
#include <hip/hip_runtime.h>

#define FEAT 128
#define NP   256
#define NG   1024
#define PT   16
#define GT   32
#define LDP  132   // row pitch (floats); 528B = 16B-aligned, yv row-stride-1 reads are 2-way (free)
#define EPSB 1e-5f

#define FMA4(acc, xv, vv) \
    acc = fmaf((xv).x, (vv).x, acc); \
    acc = fmaf((xv).y, (vv).y, acc); \
    acc = fmaf((xv).z, (vv).z, acc); \
    acc = fmaf((xv).w, (vv).w, acc);

// z0 = -2*y*v0, z1 = -2*y*v1, b0 += y^2*v0, b1 += y^2*v1
__device__ __forceinline__ void yv_one(const float4 y, const float4 v0, const float4 v1,
                                       float4& z0, float4& z1, float& b0, float& b1) {
    z0.x = -2.f * y.x * v0.x; z1.x = -2.f * y.x * v1.x;
    b0 = fmaf(y.x * y.x, v0.x, b0); b1 = fmaf(y.x * y.x, v1.x, b1);
    z0.y = -2.f * y.y * v0.y; z1.y = -2.f * y.y * v1.y;
    b0 = fmaf(y.y * y.y, v0.y, b0); b1 = fmaf(y.y * y.y, v1.y, b1);
    z0.z = -2.f * y.z * v0.z; z1.z = -2.f * y.z * v1.z;
    b0 = fmaf(y.z * y.z, v0.z, b0); b1 = fmaf(y.z * y.z, v1.z, b1);
    z0.w = -2.f * y.w * v0.w; z1.w = -2.f * y.w * v1.w;
    b0 = fmaf(y.w * y.w, v0.w, b0); b1 = fmaf(y.w * y.w, v1.w, b1);
}

// a0 += x^2*v0, a1 += x^2*v1
__device__ __forceinline__ void a_one(const float4 x, const float4 v0, const float4 v1,
                                      float& a0, float& a1) {
    a0 = fmaf(x.x * x.x, v0.x, a0); a1 = fmaf(x.x * x.x, v1.x, a1);
    a0 = fmaf(x.y * x.y, v0.y, a0); a1 = fmaf(x.y * x.y, v1.y, a1);
    a0 = fmaf(x.z * x.z, v0.z, a0); a1 = fmaf(x.z * x.z, v1.z, a1);
    a0 = fmaf(x.w * x.w, v0.w, a0); a1 = fmaf(x.w * x.w, v1.w, a1);
}

__global__ __launch_bounds__(256) void CLASSIFIER_69956427317336_kernel(
    const float* __restrict__ px,   // [NP][FEAT]
    const float* __restrict__ gx,   // [NG][FEAT]
    const float* __restrict__ bw,
    const float* __restrict__ bb,
    const float* __restrict__ bm,
    const float* __restrict__ bv,
    const float* __restrict__ Wm,   // [2][FEAT]
    const float* __restrict__ bias, // [2]
    float* __restrict__ out)        // [NP][NG][2]
{
    __shared__ __align__(16) float xs[PT][LDP];
    __shared__ __align__(16) float yv0s[GT][LDP];
    __shared__ __align__(16) float yv1s[GT][LDP];
    __shared__ __align__(16) float V0[FEAT];
    __shared__ __align__(16) float V1[FEAT];
    __shared__ float Ash[PT][2];
    __shared__ float Bsh[GT][2];
    __shared__ float kpart[4];
    __shared__ float Ksh[2];

    const int tid = threadIdx.x;
    const int p0 = blockIdx.x * PT;
    const int g0 = blockIdx.y * GT;

    // ---- phase 0: issue tile loads into registers (each load inst is a dense segment) ----
    const int gg = tid >> 3, ge = tid & 7;     // g row 0..31, f-chunk 0..7
    const float4* grow = (const float4*)(gx + (size_t)(g0 + gg) * FEAT);
    float4 gv0 = grow[ge];
    float4 gv1 = grow[ge + 8];
    float4 gv2 = grow[ge + 16];
    float4 gv3 = grow[ge + 24];

    const int pp = tid >> 4, pe = tid & 15;    // p row 0..15, f-chunk 0..15
    const float4* prow = (const float4*)(px + (size_t)(p0 + pp) * FEAT);
    float4 pv0 = prow[pe];
    float4 pv1 = prow[pe + 16];

    // ---- fold BN+linear: V[c][f] = bw*rsqrt(bv+eps)*W[c][f]; K[c] = b[c]+Σ(bb−bm*inv)W ----
    {
        const int c = tid >> 7, f = tid & 127;
        const float inv = bw[f] * rsqrtf(bv[f] + EPSB);
        const float wv  = Wm[c * FEAT + f];
        const float v   = inv * wv;
        if (c == 0) V0[f] = v; else V1[f] = v;
        float kt = (bb[f] - bm[f] * inv) * wv;
        #pragma unroll
        for (int off = 32; off > 0; off >>= 1) kt += __shfl_down(kt, off);
        if ((tid & 63) == 0) kpart[tid >> 6] = kt;   // waves 0,1 -> c=0; 2,3 -> c=1
    }
    __syncthreads();
    if (tid < 2) Ksh[tid] = bias[tid] + kpart[tid * 2] + kpart[tid * 2 + 1];

    // ---- phase 1a: yv tiles (−2·y·V) + B[g,c] = Σ y²V ----
    {
        float b0 = 0.f, b1 = 0.f;
        float4* w0 = (float4*)&yv0s[gg][0];
        float4* w1 = (float4*)&yv1s[gg][0];
        const float4* v0p = (const float4*)V0;
        const float4* v1p = (const float4*)V1;
        float4 z0, z1;
        yv_one(gv0, v0p[ge],      v1p[ge],      z0, z1, b0, b1); w0[ge]      = z0; w1[ge]      = z1;
        yv_one(gv1, v0p[ge + 8],  v1p[ge + 8],  z0, z1, b0, b1); w0[ge + 8]  = z0; w1[ge + 8]  = z1;
        yv_one(gv2, v0p[ge + 16], v1p[ge + 16], z0, z1, b0, b1); w0[ge + 16] = z0; w1[ge + 16] = z1;
        yv_one(gv3, v0p[ge + 24], v1p[ge + 24], z0, z1, b0, b1); w0[ge + 24] = z0; w1[ge + 24] = z1;
        #pragma unroll
        for (int off = 4; off > 0; off >>= 1) {
            b0 += __shfl_down(b0, off, 8);
            b1 += __shfl_down(b1, off, 8);
        }
        if (ge == 0) { Bsh[gg][0] = b0; Bsh[gg][1] = b1; }
    }

    // ---- phase 1b: xs tile + A[p,c] = Σ x²V ----
    {
        float a0 = 0.f, a1 = 0.f;
        float4* wx = (float4*)&xs[pp][0];
        const float4* v0p = (const float4*)V0;
        const float4* v1p = (const float4*)V1;
        wx[pe]      = pv0;
        wx[pe + 16] = pv1;
        a_one(pv0, v0p[pe],      v1p[pe],      a0, a1);
        a_one(pv1, v0p[pe + 16], v1p[pe + 16], a0, a1);
        #pragma unroll
        for (int off = 8; off > 0; off >>= 1) {
            a0 += __shfl_down(a0, off, 16);
            a1 += __shfl_down(a1, off, 16);
        }
        if (pe == 0) { Ash[pp][0] = a0; Ash[pp][1] = a1; }
    }
    __syncthreads();

    // ---- main: thread (pi, j) computes (p0+pi, g0+j) and (p0+pi, g0+j+16), both classes ----
    const int pi = tid >> 4, j = tid & 15;
    float acc00 = Ash[pi][0] + Bsh[j][0]      + Ksh[0];
    float acc01 = Ash[pi][1] + Bsh[j][1]      + Ksh[1];
    float acc10 = Ash[pi][0] + Bsh[j + 16][0] + Ksh[0];
    float acc11 = Ash[pi][1] + Bsh[j + 16][1] + Ksh[1];

    const float4* xr  = (const float4*)&xs[pi][0];
    const float4* y0a = (const float4*)&yv0s[j][0];
    const float4* y1a = (const float4*)&yv1s[j][0];
    const float4* y0b = (const float4*)&yv0s[j + 16][0];
    const float4* y1b = (const float4*)&yv1s[j + 16][0];

    #pragma unroll 4
    for (int i = 0; i < FEAT / 4; ++i) {
        const float4 xv  = xr[i];
        const float4 a0v = y0a[i], a1v = y1a[i];
        const float4 b0v = y0b[i], b1v = y1b[i];
        FMA4(acc00, xv, a0v)
        FMA4(acc01, xv, a1v)
        FMA4(acc10, xv, b0v)
        FMA4(acc11, xv, b1v)
    }

    const size_t ob = ((size_t)(p0 + pi) * NG + (size_t)(g0 + j)) * 2;
    *(float2*)(out + ob)      = make_float2(acc00, acc01);
    *(float2*)(out + ob + 32) = make_float2(acc10, acc11);
}

extern "C" void kernel_launch(void* const* d_in, const int* in_sizes, int n_in,
                              void* d_out, int out_size, void* d_ws, size_t ws_size,
                              hipStream_t stream) {
    (void)in_sizes; (void)n_in; (void)out_size; (void)d_ws; (void)ws_size;
    const float* px = (const float*)d_in[0];
    const float* gx = (const float*)d_in[1];
    const float* bw = (const float*)d_in[2];
    const float* bb = (const float*)d_in[3];
    const float* bm = (const float*)d_in[4];
    const float* bv = (const float*)d_in[5];
    const float* Wm = (const float*)d_in[6];
    const float* bs = (const float*)d_in[7];
    float* out = (float*)d_out;

    dim3 grid(NP / PT, NG / GT);   // 16 x 32 = 512 blocks, 2 per CU
    dim3 block(256);
    CLASSIFIER_69956427317336_kernel<<<grid, block, 0, stream>>>(
        px, gx, bw, bb, bm, bv, Wm, bs, out);
}

// Round 3
// 12.962 us; speedup vs baseline: 1.0531x; 1.0531x over previous
//
#include <hip/hip_runtime.h>

#define FEAT 128
#define NP   256
#define NG   1024
#define PT   16
#define GT   32
#define LDP  132   // row pitch (floats); j vs j+8 rows are a free 2-way bank alias
#define EPSB 1e-5f

#define FMA4(acc, xv, vv) \
    acc = fmaf((xv).x, (vv).x, acc); \
    acc = fmaf((xv).y, (vv).y, acc); \
    acc = fmaf((xv).z, (vv).z, acc); \
    acc = fmaf((xv).w, (vv).w, acc);

// One component of the g-side fold:
//   inv = bw*rsqrt(bv+eps); v0 = inv*W0; v1 = inv*W1
//   z = -2*y*v; B' += y^2*v + (bb - bm*inv)*W   (K-term folded in)
#define GFOLD(C) { \
    const float inv = pbw.C * rsqrtf(pbv.C + EPSB); \
    const float v0  = inv * pw0.C; \
    const float v1  = inv * pw1.C; \
    const float y   = yv.C; \
    z0.C = -2.f * y * v0; \
    z1.C = -2.f * y * v1; \
    const float kt = pbb.C - pbm.C * inv; \
    b0 = fmaf(y * y, v0, fmaf(kt, pw0.C, b0)); \
    b1 = fmaf(y * y, v1, fmaf(kt, pw1.C, b1)); }

// One component of the x-side fold: A += x^2 * inv * W
#define XFOLD(C) { \
    const float inv = qbw.C * rsqrtf(qbv.C + EPSB); \
    const float t   = xv.C * xv.C; \
    a0 = fmaf(t, inv * qw0.C, a0); \
    a1 = fmaf(t, inv * qw1.C, a1); }

__global__ __launch_bounds__(256) void CLASSIFIER_69956427317336_kernel(
    const float* __restrict__ px,   // [NP][FEAT]
    const float* __restrict__ gx,   // [NG][FEAT]
    const float* __restrict__ bw,
    const float* __restrict__ bb,
    const float* __restrict__ bm,
    const float* __restrict__ bv,
    const float* __restrict__ Wm,   // [2][FEAT]
    const float* __restrict__ bias, // [2]
    float* __restrict__ out)        // [NP][NG][2]
{
    __shared__ __align__(16) float xs[PT][LDP];
    __shared__ __align__(16) float z0s[GT][LDP];
    __shared__ __align__(16) float z1s[GT][LDP];
    __shared__ float Ash[PT][2];
    __shared__ float Bsh[GT][2];

    const int tid = threadIdx.x;
    const int p0 = blockIdx.x * PT;
    const int g0 = blockIdx.y * GT;

    const float4* bw4 = (const float4*)bw;
    const float4* bb4 = (const float4*)bb;
    const float4* bm4 = (const float4*)bm;
    const float4* bv4 = (const float4*)bv;
    const float4* Wm4 = (const float4*)Wm;   // [2][32] float4

    const float bias0 = bias[0];
    const float bias1 = bias[1];

    // ---- g-side: thread (gg,ge) owns g-row gg, f4-chunks {ge, ge+8, ge+16, ge+24} ----
    const int gg = tid >> 3, ge = tid & 7;
    const float4* grow = (const float4*)(gx + (size_t)(g0 + gg) * FEAT);

    // ---- x-side: thread (pp,pe) owns p-row pp, f4-chunks {pe, pe+16} ----
    const int pp = tid >> 4, pe = tid & 15;
    const float4* prow = (const float4*)(px + (size_t)(p0 + pp) * FEAT);
    const float4 xv0 = prow[pe];
    const float4 xv1 = prow[pe + 16];
    const float4 qbw0 = bw4[pe], qbw1 = bw4[pe + 16];
    const float4 qbv0 = bv4[pe], qbv1 = bv4[pe + 16];
    const float4 qw00 = Wm4[pe], qw01 = Wm4[pe + 16];
    const float4 qw10 = Wm4[32 + pe], qw11 = Wm4[32 + pe + 16];

    // g-side fold: z tiles + B'[g,c] (B + K folded, since the 8-lane group covers all 128 f)
    float b0 = 0.f, b1 = 0.f;
    {
        float4* w0 = (float4*)&z0s[gg][0];
        float4* w1 = (float4*)&z1s[gg][0];
        #pragma unroll
        for (int k = 0; k < 4; ++k) {
            const int idx = ge + 8 * k;
            const float4 yv  = grow[idx];
            const float4 pbw = bw4[idx];
            const float4 pbv = bv4[idx];
            const float4 pbm = bm4[idx];
            const float4 pbb = bb4[idx];
            const float4 pw0 = Wm4[idx];
            const float4 pw1 = Wm4[32 + idx];
            float4 z0, z1;
            GFOLD(x) GFOLD(y) GFOLD(z) GFOLD(w)
            w0[idx] = z0;
            w1[idx] = z1;
        }
        #pragma unroll
        for (int off = 4; off > 0; off >>= 1) {
            b0 += __shfl_down(b0, off, 8);
            b1 += __shfl_down(b1, off, 8);
        }
        if (ge == 0) { Bsh[gg][0] = b0; Bsh[gg][1] = b1; }
    }

    // x-side fold: xs tile + A[p,c]
    {
        float a0 = 0.f, a1 = 0.f;
        float4* wx = (float4*)&xs[pp][0];
        wx[pe]      = xv0;
        wx[pe + 16] = xv1;
        { const float4 xv = xv0, qbw = qbw0, qbv = qbv0, qw0 = qw00, qw1 = qw10;
          XFOLD(x) XFOLD(y) XFOLD(z) XFOLD(w) }
        { const float4 xv = xv1, qbw = qbw1, qbv = qbv1, qw0 = qw01, qw1 = qw11;
          XFOLD(x) XFOLD(y) XFOLD(z) XFOLD(w) }
        #pragma unroll
        for (int off = 8; off > 0; off >>= 1) {
            a0 += __shfl_down(a0, off, 16);
            a1 += __shfl_down(a1, off, 16);
        }
        if (pe == 0) { Ash[pp][0] = a0; Ash[pp][1] = a1; }
    }
    __syncthreads();   // the ONLY barrier

    // ---- main: thread (pi,j) computes (p0+pi, g0+j) and (p0+pi, g0+j+16), both classes ----
    const int pi = tid >> 4, j = tid & 15;
    float acc00 = 0.f, acc01 = 0.f, acc10 = 0.f, acc11 = 0.f;

    const float4* xr  = (const float4*)&xs[pi][0];
    const float4* y0a = (const float4*)&z0s[j][0];
    const float4* y1a = (const float4*)&z1s[j][0];
    const float4* y0b = (const float4*)&z0s[j + 16][0];
    const float4* y1b = (const float4*)&z1s[j + 16][0];

    #pragma unroll 4
    for (int i = 0; i < FEAT / 4; ++i) {
        const float4 xv  = xr[i];
        const float4 a0v = y0a[i], a1v = y1a[i];
        const float4 b0v = y0b[i], b1v = y1b[i];
        FMA4(acc00, xv, a0v)
        FMA4(acc01, xv, a1v)
        FMA4(acc10, xv, b0v)
        FMA4(acc11, xv, b1v)
    }

    acc00 += Ash[pi][0] + Bsh[j][0]      + bias0;
    acc01 += Ash[pi][1] + Bsh[j][1]      + bias1;
    acc10 += Ash[pi][0] + Bsh[j + 16][0] + bias0;
    acc11 += Ash[pi][1] + Bsh[j + 16][1] + bias1;

    const size_t ob = ((size_t)(p0 + pi) * NG + (size_t)(g0 + j)) * 2;
    *(float2*)(out + ob)      = make_float2(acc00, acc01);
    *(float2*)(out + ob + 32) = make_float2(acc10, acc11);
}

extern "C" void kernel_launch(void* const* d_in, const int* in_sizes, int n_in,
                              void* d_out, int out_size, void* d_ws, size_t ws_size,
                              hipStream_t stream) {
    (void)in_sizes; (void)n_in; (void)out_size; (void)d_ws; (void)ws_size;
    const float* px = (const float*)d_in[0];
    const float* gx = (const float*)d_in[1];
    const float* bw = (const float*)d_in[2];
    const float* bb = (const float*)d_in[3];
    const float* bm = (const float*)d_in[4];
    const float* bv = (const float*)d_in[5];
    const float* Wm = (const float*)d_in[6];
    const float* bs = (const float*)d_in[7];
    float* out = (float*)d_out;

    dim3 grid(NP / PT, NG / GT);   // 16 x 32 = 512 blocks, 2 per CU
    dim3 block(256);
    CLASSIFIER_69956427317336_kernel<<<grid, block, 0, stream>>>(
        px, gx, bw, bb, bm, bv, Wm, bs, out);
}